// Round 5
// baseline (246.683 us; speedup 1.0000x reference)
//
#include <hip/hip_runtime.h>
#include <hip/hip_bf16.h>

#define NROWS 32768
#define DDIM  4096
#define ODIM  256
#define EPSV  1e-5f

#define CHUNKS 128
#define RPC    256      // rows per chunk (CHUNKS*RPC == NROWS)

#define BM 128
#define BK 64
#define NKT (DDIM / BK)   // 64 K-steps

typedef __attribute__((ext_vector_type(4))) float          f32x4;
typedef __attribute__((ext_vector_type(8))) __bf16         bf16x8;
typedef __attribute__((ext_vector_type(8))) unsigned short u16x8;
typedef __attribute__((ext_vector_type(4))) unsigned short u16x4;

static __device__ __forceinline__ unsigned short f2bf(float f) {
  return __builtin_bit_cast(unsigned short, __float2bfloat16(f));
}

// ---------------- k1: per-chunk column partial sums (R1-proven) ----------------
__global__ __launch_bounds__(256) void k1_stats(const float* __restrict__ x,
                                                float* __restrict__ psum,
                                                float* __restrict__ psq) {
  const int col = blockIdx.x * 1024 + threadIdx.x * 4;
  const float* p = x + (size_t)blockIdx.y * RPC * DDIM + col;
  f32x4 s = {0.f, 0.f, 0.f, 0.f};
  f32x4 q = {0.f, 0.f, 0.f, 0.f};
#pragma unroll 8
  for (int r = 0; r < RPC; ++r) {
    f32x4 v = *(const f32x4*)p;
    p += DDIM;
    s += v;
    q += v * v;
  }
  *(f32x4*)(psum + (size_t)blockIdx.y * DDIM + col) = s;
  *(f32x4*)(psq  + (size_t)blockIdx.y * DDIM + col) = q;
}

// ---------------- k2a: finalize mean/var -> scale/shift ----------------
__global__ __launch_bounds__(256) void k2_stats_finalize(
    const float* __restrict__ psum, const float* __restrict__ psq,
    const float* __restrict__ gamma, const float* __restrict__ beta,
    float* __restrict__ scale, float* __restrict__ shift) {
  __shared__ float ss[4][64];
  __shared__ float sq[4][64];
  const int lane = threadIdx.x & 63;
  const int g    = threadIdx.x >> 6;          // 0..3
  const int d    = blockIdx.x * 64 + lane;
  float s = 0.f, qq = 0.f;
  for (int c = g * 32; c < (g + 1) * 32; ++c) {
    s  += psum[(size_t)c * DDIM + d];
    qq += psq [(size_t)c * DDIM + d];
  }
  ss[g][lane] = s;
  sq[g][lane] = qq;
  __syncthreads();
  if (g == 0) {
    s  = ss[0][lane] + ss[1][lane] + ss[2][lane] + ss[3][lane];
    qq = sq[0][lane] + sq[1][lane] + sq[2][lane] + sq[3][lane];
    const float inv = 1.0f / (float)NROWS;
    const float mean = s * inv;
    const float var  = fmaxf(qq * inv - mean * mean, 0.f);
    const float a = gamma[d] * rsqrtf(var + EPSV);
    scale[d] = a;
    shift[d] = beta[d] - mean * a;
  }
}

// ---------------- k2b: W fp32 -> bf16 ----------------
__global__ __launch_bounds__(256) void k2_wconv(const float* __restrict__ Wf,
                                                unsigned short* __restrict__ Wb) {
  const size_t i = ((size_t)blockIdx.x * 256 + threadIdx.x) * 4;
  f32x4 v = *(const f32x4*)(Wf + i);
  u16x4 o;
  o[0] = f2bf(v[0]); o[1] = f2bf(v[1]); o[2] = f2bf(v[2]); o[3] = f2bf(v[3]);
  *(u16x4*)(Wb + i) = o;
}

// ---------------- k3: fused normalize+relu+bf16 GEMM, depth-2 A pipeline -------
// Per step t (buffers CUR=t&1):
//   issue B(t+1)->Bs[CUR^1] ; issue A(t+2)->regset[CUR] ; MFMA(t)
//   vmcnt(8)  -> A(t+1) landed ; transform+ds_write -> As[CUR^1]
//   vmcnt(4) lgkmcnt(0) -> B(t+1) in LDS, A(t+2) STAYS in flight ; s_barrier
__global__ __launch_bounds__(512, 1) void k3_bn_gemm(
    const float* __restrict__ x,
    const unsigned short* __restrict__ Wb,
    const float* __restrict__ scale,
    const float* __restrict__ shift,
    const float* __restrict__ bias,
    float* __restrict__ out) {
  __shared__ unsigned short As[2][BM * BK];     // 2 x 16 KB, XOR-swizzled
  __shared__ unsigned short Bs[2][ODIM * BK];   // 2 x 32 KB, XOR-swizzled
  __shared__ float SF[DDIM];                    // 16 KB scale
  __shared__ float SH[DDIM];                    // 16 KB shift

  const int tid = threadIdx.x;
  const int l   = tid & 63;
  const int w   = tid >> 6;     // 0..7
  const int wr  = w >> 2;       // 0..1
  const int wc  = w & 3;        // 0..3
  const size_t bm0 = (size_t)blockIdx.x * BM;

  // --- scale/shift LDS preload ---
  ((f32x4*)SF)[tid * 2]     = ((const f32x4*)scale)[tid * 2];
  ((f32x4*)SF)[tid * 2 + 1] = ((const f32x4*)scale)[tid * 2 + 1];
  ((f32x4*)SH)[tid * 2]     = ((const f32x4*)shift)[tid * 2];
  ((f32x4*)SH)[tid * 2 + 1] = ((const f32x4*)shift)[tid * 2 + 1];

  // --- A staging geometry: thread covers rows rA, rA+64; 8-col unit uA ---
  const int rA = tid >> 3;      // 0..63
  const int uA = tid & 7;       // 0..7
  const float* xp0 = x + (bm0 + rA) * (size_t)DDIM + uA * 8;
  const float* xp1 = xp0 + (size_t)64 * DDIM;
  const int awo = rA * 64 + ((uA ^ (rA & 7)) << 3);   // ushort offset in buf
  int ktb = uA * 8;                                   // scale/shift col base

  // --- B staging: gl_lds, linear LDS dest + inverse-swizzled global src ---
  const unsigned short* bsrc[4];
#pragma unroll
  for (int q = 0; q < 4; ++q) {
    const int p  = w * 256 + q * 64 + l;
    const int o  = p >> 3;
    const int up = p & 7;
    bsrc[q] = Wb + (size_t)o * DDIM + ((up ^ (o & 7)) << 3);
  }

  // --- fragment LDS offsets (ushort units); kk -> ^32 ---
  int offA[4], offB[4];
#pragma unroll
  for (int i = 0; i < 4; ++i) {
    const int row = wr * 64 + i * 16 + (l & 15);
    offA[i] = row * 64 + (((l >> 4) ^ (row & 7)) << 3);
  }
#pragma unroll
  for (int j = 0; j < 4; ++j) {
    const int row = wc * 64 + j * 16 + (l & 15);
    offB[j] = row * 64 + (((l >> 4) ^ (row & 7)) << 3);
  }

  const f32x4 zero = {0.f, 0.f, 0.f, 0.f};
  f32x4 acc[4][4];
#pragma unroll
  for (int i = 0; i < 4; ++i)
#pragma unroll
    for (int j = 0; j < 4; ++j) acc[i][j] = zero;

  // two A register sets (static indices only)
  f32x4 sA0[4], sA1[4];

#define ISSUE_A(S)                                                             \
  asm volatile("global_load_dwordx4 %0, %1, off" : "=v"(S[0]) : "v"(xp0));     \
  asm volatile("global_load_dwordx4 %0, %1, off" : "=v"(S[1]) : "v"(xp0 + 4)); \
  asm volatile("global_load_dwordx4 %0, %1, off" : "=v"(S[2]) : "v"(xp1));     \
  asm volatile("global_load_dwordx4 %0, %1, off" : "=v"(S[3]) : "v"(xp1 + 4)); \
  xp0 += BK; xp1 += BK;                                                        \
  asm volatile("" ::: "memory");

#define ISSUE_B(BUFI)                                                          \
  _Pragma("unroll")                                                            \
  for (int q = 0; q < 4; ++q) {                                                \
    __builtin_amdgcn_global_load_lds(                                          \
        (__attribute__((address_space(1))) void*)bsrc[q],                      \
        (__attribute__((address_space(3))) void*)(                             \
            &Bs[BUFI][(w * 256 + q * 64) * 8]),                                \
        16, 0, 0);                                                             \
    bsrc[q] += BK;                                                             \
  }                                                                            \
  asm volatile("" ::: "memory");

#define TRANSFORM_WRITE(BUFI, S)                                               \
  {                                                                            \
    f32x4 sa0 = *(const f32x4*)&SF[ktb];                                       \
    f32x4 sa1 = *(const f32x4*)&SF[ktb + 4];                                   \
    f32x4 sc0 = *(const f32x4*)&SH[ktb];                                       \
    f32x4 sc1 = *(const f32x4*)&SH[ktb + 4];                                   \
    ktb += BK;                                                                 \
    u16x8 pk0, pk1;                                                            \
    _Pragma("unroll")                                                          \
    for (int e = 0; e < 4; ++e) {                                              \
      pk0[e]     = f2bf(fmaxf(S[0][e] * sa0[e] + sc0[e], 0.f));                \
      pk0[e + 4] = f2bf(fmaxf(S[1][e] * sa1[e] + sc1[e], 0.f));                \
      pk1[e]     = f2bf(fmaxf(S[2][e] * sa0[e] + sc0[e], 0.f));                \
      pk1[e + 4] = f2bf(fmaxf(S[3][e] * sa1[e] + sc1[e], 0.f));                \
    }                                                                          \
    *(u16x8*)&As[BUFI][awo]        = pk0;                                      \
    *(u16x8*)&As[BUFI][awo + 4096] = pk1;                                      \
  }

#define MFMA_PHASE(BUFI)                                                       \
  _Pragma("unroll")                                                            \
  for (int kk = 0; kk < 2; ++kk) {                                             \
    const int kx = kk << 5;                                                    \
    bf16x8 af[4], bfr[4];                                                      \
    _Pragma("unroll")                                                          \
    for (int i = 0; i < 4; ++i)                                                \
      af[i] = __builtin_bit_cast(bf16x8,                                       \
                                 *(const u16x8*)&As[BUFI][offA[i] ^ kx]);      \
    _Pragma("unroll")                                                          \
    for (int j = 0; j < 4; ++j)                                                \
      bfr[j] = __builtin_bit_cast(bf16x8,                                      \
                                  *(const u16x8*)&Bs[BUFI][offB[j] ^ kx]);     \
    _Pragma("unroll")                                                          \
    for (int i = 0; i < 4; ++i)                                                \
      _Pragma("unroll")                                                        \
      for (int j = 0; j < 4; ++j)                                              \
        acc[i][j] = __builtin_amdgcn_mfma_f32_16x16x32_bf16(                   \
            af[i], bfr[j], acc[i][j], 0, 0, 0);                                \
  }

  // ---- prologue: A(0)->sA0, B(0)->Bs[0], A(1)->sA1 ----
  {
    ISSUE_A(sA0);
    ISSUE_B(0);
    ISSUE_A(sA1);
    asm volatile("s_waitcnt lgkmcnt(0)" ::: "memory");   // SF/SH stores done
    __builtin_amdgcn_sched_barrier(0);
    __builtin_amdgcn_s_barrier();                        // SF/SH visible
    asm volatile("s_waitcnt vmcnt(8)" ::: "memory");     // A(0) landed
    __builtin_amdgcn_sched_barrier(0);
    TRANSFORM_WRITE(0, sA0);
    asm volatile("s_waitcnt vmcnt(4) lgkmcnt(0)" ::: "memory");  // B(0) in LDS
    __builtin_amdgcn_sched_barrier(0);
    __builtin_amdgcn_s_barrier();
  }

  // steady state: issue into Bs[CUR^1] and regset SC (=A(t+2));
  // compute [CUR]; transform regset SN (=A(t+1)) -> As[CUR^1].
#define STEP_FULL(CUR, SC, SN)                                                 \
  do {                                                                         \
    ISSUE_B((CUR) ^ 1);                                                        \
    ISSUE_A(SC);                                                               \
    MFMA_PHASE(CUR);                                                           \
    asm volatile("s_waitcnt vmcnt(8)" ::: "memory");                           \
    __builtin_amdgcn_sched_barrier(0);                                         \
    TRANSFORM_WRITE((CUR) ^ 1, SN);                                            \
    asm volatile("s_waitcnt vmcnt(4) lgkmcnt(0)" ::: "memory");                \
    __builtin_amdgcn_sched_barrier(0);                                         \
    __builtin_amdgcn_s_barrier();                                              \
  } while (0)

  // t = 0..61 (issue A up to tile 63, B up to tile 62->63 below)
  for (int kt = 0; kt < NKT - 2; kt += 2) {
    STEP_FULL(0, sA0, sA1);
    STEP_FULL(1, sA1, sA0);
  }
  // t = 62: B(63) only; A(63) is in sA1
  {
    ISSUE_B(1);
    MFMA_PHASE(0);
    asm volatile("s_waitcnt vmcnt(4)" ::: "memory");     // A(63) landed
    __builtin_amdgcn_sched_barrier(0);
    TRANSFORM_WRITE(1, sA1);
    asm volatile("s_waitcnt vmcnt(0) lgkmcnt(0)" ::: "memory");
    __builtin_amdgcn_sched_barrier(0);
    __builtin_amdgcn_s_barrier();
  }
  // t = 63
  MFMA_PHASE(1);

#undef STEP_FULL
#undef MFMA_PHASE
#undef TRANSFORM_WRITE
#undef ISSUE_B
#undef ISSUE_A

  // epilogue: C/D layout col=l&15, row=(l>>4)*4+rr
  const int cl = l & 15;
  const int rg = l >> 4;
#pragma unroll
  for (int j = 0; j < 4; ++j) {
    const int oc = wc * 64 + j * 16 + cl;
    const float bv = bias[oc];
#pragma unroll
    for (int i = 0; i < 4; ++i) {
      const size_t r0 = bm0 + wr * 64 + i * 16 + rg * 4;
#pragma unroll
      for (int rr = 0; rr < 4; ++rr) {
        out[(r0 + rr) * ODIM + oc] = acc[i][j][rr] + bv;
      }
    }
  }
}

extern "C" void kernel_launch(void* const* d_in, const int* in_sizes, int n_in,
                              void* d_out, int out_size, void* d_ws, size_t ws_size,
                              hipStream_t stream) {
  const float* x     = (const float*)d_in[0];
  const float* gamma = (const float*)d_in[1];
  const float* beta  = (const float*)d_in[2];
  const float* W     = (const float*)d_in[3];
  const float* b     = (const float*)d_in[4];
  float* out = (float*)d_out;

  float* psum  = (float*)d_ws;
  float* psq   = psum + (size_t)CHUNKS * DDIM;
  float* scale = psum + 2 * (size_t)CHUNKS * DDIM;
  float* shift = scale + DDIM;
  unsigned short* Wb = (unsigned short*)(shift + DDIM);

  k1_stats<<<dim3(4, CHUNKS), 256, 0, stream>>>(x, psum, psq);
  k2_stats_finalize<<<DDIM / 64, 256, 0, stream>>>(psum, psq, gamma, beta, scale, shift);
  k2_wconv<<<(ODIM * DDIM) / 1024, 256, 0, stream>>>(W, Wb);
  k3_bn_gemm<<<NROWS / BM, 512, 0, stream>>>(x, Wb, scale, shift, b, out);
}